// Round 1
// baseline (37085.205 us; speedup 1.0000x reference)
//
#include <hip/hip_runtime.h>
#include <hip/hip_bf16.h>
#include <cstddef>
#include <cstdint>

#define HDIM 512
#define NNODES 1024
#define NEDGES 16384
#define BATCH 32
#define SEQ 1024
#define DIN 128

// ---------------------------------------------------------------------------
// Precompute: AWp[d][j] = sum_{e: dst_e=d} Wp[src_e][j]
// ---------------------------------------------------------------------------
__global__ void scatter_awp_kernel(const float* __restrict__ Wp,
                                   const int* __restrict__ src,
                                   const int* __restrict__ dst,
                                   float* __restrict__ AWp) {
    int e = blockIdx.x;        // 16384 blocks
    int c = threadIdx.x;       // 256 threads, 2 cols each
    int s = src[e], d = dst[e];
    atomicAdd(&AWp[d * HDIM + c],        Wp[s * HDIM + c]);
    atomicAdd(&AWp[d * HDIM + 256 + c],  Wp[s * HDIM + 256 + c]);
}

__global__ void scatter_abp_kernel(const float* __restrict__ bp,
                                   const int* __restrict__ src,
                                   const int* __restrict__ dst,
                                   float* __restrict__ Abp) {
    int e = blockIdx.x * blockDim.x + threadIdx.x;
    if (e < NEDGES) atomicAdd(&Abp[dst[e]], bp[src[e]]);
}

// b_eff[i] = bias[i] + bu[i] + sum_d Wu[i][d] * Abp[d]
__global__ void beff_kernel(const float* __restrict__ Wu,
                            const float* __restrict__ Abp,
                            const float* __restrict__ bias,
                            const float* __restrict__ bu,
                            float* __restrict__ beff) {
    int i = threadIdx.x;       // 512 threads, 1 block
    float s = 0.f;
    for (int d = 0; d < NNODES; ++d) s += Wu[i * NNODES + d] * Abp[d];
    beff[i] = bias[i] + bu[i] + s;
}

// ---------------------------------------------------------------------------
// fp32 tiled GEMM: C[m][n] = sum_k A[m][k] * B_(k,n)  (+ optional addend)
//   TB == 0 : B is (K x N) row-major
//   TB == 1 : B is (N x K) row-major (i.e. compute A @ B^T)
// BM=BN=64, BK=16, 256 threads, 4x4 per thread. M,N % 64 == 0, K % 16 == 0.
// ---------------------------------------------------------------------------
template <int TB>
__global__ __launch_bounds__(256) void gemm64(const float* __restrict__ A,
                                              const float* __restrict__ B,
                                              float* __restrict__ C,
                                              const float* __restrict__ addend,
                                              int M, int N, int K) {
    const int bn = blockIdx.x, bm = blockIdx.y;
    const int tid = threadIdx.x;
    const int tx = tid & 15, ty = tid >> 4;
    const int m0 = bm * 64, n0 = bn * 64;

    __shared__ float As[16][68];   // [kk][m], row stride 272B (16B aligned)
    __shared__ float Bs[16][68];   // [kk][n]

    float acc[4][4] = {};

    for (int k0 = 0; k0 < K; k0 += 16) {
        {   // A tile 64x16 -> As[kk][m]
            int kk = tid & 15, m = tid >> 4;
            #pragma unroll
            for (int i = 0; i < 4; ++i)
                As[kk][m + 16 * i] = A[(size_t)(m0 + m + 16 * i) * K + k0 + kk];
        }
        if (TB == 0) {
            int n = tid & 63, kk = tid >> 6;
            #pragma unroll
            for (int i = 0; i < 4; ++i)
                Bs[kk + 4 * i][n] = B[(size_t)(k0 + kk + 4 * i) * N + n0 + n];
        } else {
            int kk = tid & 15, n = tid >> 4;
            #pragma unroll
            for (int i = 0; i < 4; ++i)
                Bs[kk][n + 16 * i] = B[(size_t)(n0 + n + 16 * i) * K + k0 + kk];
        }
        __syncthreads();
        #pragma unroll
        for (int kk = 0; kk < 16; ++kk) {
            float4 a4 = *reinterpret_cast<const float4*>(&As[kk][ty * 4]);
            float4 b4 = *reinterpret_cast<const float4*>(&Bs[kk][tx * 4]);
            float av[4] = {a4.x, a4.y, a4.z, a4.w};
            float bv[4] = {b4.x, b4.y, b4.z, b4.w};
            #pragma unroll
            for (int i = 0; i < 4; ++i)
                #pragma unroll
                for (int j = 0; j < 4; ++j)
                    acc[i][j] += av[i] * bv[j];
        }
        __syncthreads();
    }
    #pragma unroll
    for (int i = 0; i < 4; ++i) {
        int m = m0 + ty * 4 + i;
        #pragma unroll
        for (int j = 0; j < 4; ++j) {
            int n = n0 + tx * 4 + j;
            float v = acc[i][j];
            if (addend) v += addend[(size_t)m * N + n];
            C[(size_t)m * N + n] = v;
        }
    }
}

// ---------------------------------------------------------------------------
// Recurrent scan. Grid (8 slices, 32 batch). 256 threads.
// Each WG holds W_eff rows [slice*64, slice*64+64) in registers (128 f32/thr).
// h double-buffered in global (agent-scope atomics, cache-bypassing).
// Monotonic atomic-counter barrier among the 8 WGs of each batch element.
// u_ys is read (u) and overwritten (ys) in place, element-wise per step.
// ---------------------------------------------------------------------------
__launch_bounds__(256, 1)
__global__ void scan_kernel(const float* __restrict__ Weff,
                            const float* __restrict__ beff,
                            float* __restrict__ u_ys,        // (B,S,H) in/out
                            float* __restrict__ hbufs,       // 2*B*H
                            unsigned int* __restrict__ cnt,  // B counters
                            float leak) {
    const int slice = blockIdx.x;   // 0..7
    const int b = blockIdx.y;       // 0..31
    const int tid = threadIdx.x;
    const int kq = tid & 3;         // col-quarter
    const int rloc = tid >> 2;      // 0..63
    const int r = slice * 64 + rloc;

    __shared__ float hs[HDIM];

    // weight slice -> registers (fully unrolled so it stays in VGPRs)
    float w[128];
    {
        const float4* wrow =
            reinterpret_cast<const float4*>(Weff + (size_t)r * HDIM + kq * 128);
        #pragma unroll
        for (int k = 0; k < 32; ++k) {
            float4 v = wrow[k];
            w[4 * k] = v.x; w[4 * k + 1] = v.y;
            w[4 * k + 2] = v.z; w[4 * k + 3] = v.w;
        }
    }
    const float be = beff[r];
    const float lk = leak, olk = 1.0f - leak;
    float* ub = u_ys + (size_t)b * SEQ * HDIM;
    unsigned int* cb = cnt + b;

    for (int t = 0; t < SEQ; ++t) {
        const float* hr = hbufs + (size_t)(t & 1) * BATCH * HDIM + (size_t)b * HDIM;
        float* hw = hbufs + (size_t)((t + 1) & 1) * BATCH * HDIM + (size_t)b * HDIM;

        // previous h -> LDS (agent-scope loads bypass stale per-XCD caches)
        float h0 = __hip_atomic_load(hr + 2 * tid,     __ATOMIC_RELAXED, __HIP_MEMORY_SCOPE_AGENT);
        float h1 = __hip_atomic_load(hr + 2 * tid + 1, __ATOMIC_RELAXED, __HIP_MEMORY_SCOPE_AGENT);
        hs[2 * tid] = h0;
        hs[2 * tid + 1] = h1;
        __syncthreads();

        // matvec: this thread covers cols [kq*128, kq*128+128) of row r
        float acc = 0.f;
        const float* hq = hs + kq * 128;
        #pragma unroll
        for (int k = 0; k < 32; ++k) {
            float4 h4 = reinterpret_cast<const float4*>(hq)[k];
            acc += w[4 * k] * h4.x;
            acc += w[4 * k + 1] * h4.y;
            acc += w[4 * k + 2] * h4.z;
            acc += w[4 * k + 3] * h4.w;
        }
        acc += __shfl_xor(acc, 1);
        acc += __shfl_xor(acc, 2);

        if (kq == 0) {
            float pre = acc + ub[(size_t)t * HDIM + r] + be;
            float hn = tanhf(pre);
            float hnew = olk * hs[r] + lk * hn;
            __hip_atomic_store(hw + r, hnew, __ATOMIC_RELAXED, __HIP_MEMORY_SCOPE_AGENT);
            ub[(size_t)t * HDIM + r] = hnew;   // ys output, in place over u
        }
        __syncthreads();   // each thread's stores drained (vmcnt 0) at barrier

        // inter-WG barrier for this batch element (monotonic counter)
        if (tid == 0) {
            __hip_atomic_fetch_add(cb, 1u, __ATOMIC_RELEASE, __HIP_MEMORY_SCOPE_AGENT);
            const unsigned int target = 8u * (unsigned)(t + 1);
            while (__hip_atomic_load(cb, __ATOMIC_ACQUIRE, __HIP_MEMORY_SCOPE_AGENT) < target) {
                __builtin_amdgcn_s_sleep(1);
            }
        }
        __syncthreads();
    }
}

// ---------------------------------------------------------------------------
extern "C" void kernel_launch(void* const* d_in, const int* in_sizes, int n_in,
                              void* d_out, int out_size, void* d_ws, size_t ws_size,
                              hipStream_t stream) {
    const float* x      = (const float*)d_in[0];
    const int*   edges  = (const int*)d_in[1];
    const float* W_in0  = (const float*)d_in[2];
    const float* W_res0 = (const float*)d_in[3];
    const float* bias0  = (const float*)d_in[4];
    const float* Wp0    = (const float*)d_in[5];
    const float* bp0    = (const float*)d_in[6];
    const float* Wu0    = (const float*)d_in[7];
    const float* bu0    = (const float*)d_in[8];
    const float* W_in1  = (const float*)d_in[9];
    const float* W_res1 = (const float*)d_in[10];
    const float* bias1  = (const float*)d_in[11];
    const float* Wp1    = (const float*)d_in[12];
    const float* bp1    = (const float*)d_in[13];
    const float* Wu1    = (const float*)d_in[14];
    const float* bu1    = (const float*)d_in[15];

    const int* src = edges;
    const int* dst = edges + NEDGES;
    float* out = (float*)d_out;

    // workspace layout
    char* base = (char*)d_ws;
    float* ws_u  = (float*)base;                 // 32*1024*512*4 = 67,108,864
    char* p = base + (size_t)67108864;
    float* AWp   = (float*)p;  p += 2097152;     // 1024*512*4
    float* Abp   = (float*)p;  p += 4096;        // 1024*4
    float* Weff0 = (float*)p;  p += 1048576;     // 512*512*4
    float* Weff1 = (float*)p;  p += 1048576;
    float* beff0 = (float*)p;  p += 2048;
    float* beff1 = (float*)p;  p += 2048;
    float* hbufs = (float*)p;  p += 131072;      // 2*32*512*4
    unsigned int* cnt = (unsigned int*)p;        // 64 uints (2 scans x 32)

    // ---- layer 0 effective weights ----
    hipMemsetAsync(AWp, 0, 2097152 + 4096, stream);
    scatter_awp_kernel<<<NEDGES, 256, 0, stream>>>(Wp0, src, dst, AWp);
    scatter_abp_kernel<<<NEDGES / 256, 256, 0, stream>>>(bp0, src, dst, Abp);
    gemm64<0><<<dim3(8, 8), 256, 0, stream>>>(Wu0, AWp, Weff0, W_res0, 512, 512, 1024);
    beff_kernel<<<1, 512, 0, stream>>>(Wu0, Abp, bias0, bu0, beff0);

    // ---- layer 1 effective weights ----
    hipMemsetAsync(AWp, 0, 2097152 + 4096, stream);
    scatter_awp_kernel<<<NEDGES, 256, 0, stream>>>(Wp1, src, dst, AWp);
    scatter_abp_kernel<<<NEDGES / 256, 256, 0, stream>>>(bp1, src, dst, Abp);
    gemm64<0><<<dim3(8, 8), 256, 0, stream>>>(Wu1, AWp, Weff1, W_res1, 512, 512, 1024);
    beff_kernel<<<1, 512, 0, stream>>>(Wu1, Abp, bias1, bu1, beff1);

    // ---- u0 = x @ W_in0^T : (32768 x 128) @ (512 x 128)^T ----
    gemm64<1><<<dim3(512 / 64, 32768 / 64), 256, 0, stream>>>(
        x, W_in0, ws_u, nullptr, BATCH * SEQ, HDIM, DIN);

    // ---- layer 0 scan (in place over ws_u) ----
    hipMemsetAsync(hbufs, 0, 131072 + 256, stream);
    scan_kernel<<<dim3(8, BATCH), 256, 0, stream>>>(Weff0, beff0, ws_u, hbufs, cnt, 0.1f);

    // ---- u1 = ys0 @ W_in1^T : (32768 x 512) @ (512 x 512)^T -> d_out ----
    gemm64<1><<<dim3(512 / 64, 32768 / 64), 256, 0, stream>>>(
        ws_u, W_in1, out, nullptr, BATCH * SEQ, HDIM, HDIM);

    // ---- layer 1 scan (in place over d_out) ----
    hipMemsetAsync(hbufs, 0, 131072, stream);
    scan_kernel<<<dim3(8, BATCH), 256, 0, stream>>>(Weff1, beff1, out, hbufs, cnt + BATCH, 0.15f);
}

// Round 2
// 30797.101 us; speedup vs baseline: 1.2042x; 1.2042x over previous
//
#include <hip/hip_runtime.h>
#include <hip/hip_bf16.h>
#include <cstddef>
#include <cstdint>

#define HDIM 512
#define NNODES 1024
#define NEDGES 16384
#define BATCH 32
#define SEQ 1024
#define DIN 128

// ---------------------------------------------------------------------------
// Precompute: AWp[d][j] = sum_{e: dst_e=d} Wp[src_e][j]
// ---------------------------------------------------------------------------
__global__ void scatter_awp_kernel(const float* __restrict__ Wp,
                                   const int* __restrict__ src,
                                   const int* __restrict__ dst,
                                   float* __restrict__ AWp) {
    int e = blockIdx.x;        // 16384 blocks
    int c = threadIdx.x;       // 256 threads, 2 cols each
    int s = src[e], d = dst[e];
    atomicAdd(&AWp[d * HDIM + c],        Wp[s * HDIM + c]);
    atomicAdd(&AWp[d * HDIM + 256 + c],  Wp[s * HDIM + 256 + c]);
}

__global__ void scatter_abp_kernel(const float* __restrict__ bp,
                                   const int* __restrict__ src,
                                   const int* __restrict__ dst,
                                   float* __restrict__ Abp) {
    int e = blockIdx.x * blockDim.x + threadIdx.x;
    if (e < NEDGES) atomicAdd(&Abp[dst[e]], bp[src[e]]);
}

// b_eff[i] = bias[i] + bu[i] + sum_d Wu[i][d] * Abp[d]
__global__ void beff_kernel(const float* __restrict__ Wu,
                            const float* __restrict__ Abp,
                            const float* __restrict__ bias,
                            const float* __restrict__ bu,
                            float* __restrict__ beff) {
    int i = threadIdx.x;       // 512 threads, 1 block
    float s = 0.f;
    for (int d = 0; d < NNODES; ++d) s += Wu[i * NNODES + d] * Abp[d];
    beff[i] = bias[i] + bu[i] + s;
}

// ---------------------------------------------------------------------------
// fp32 tiled GEMM: C[m][n] = sum_k A[m][k] * B_(k,n)  (+ optional addend)
//   TB == 0 : B is (K x N) row-major
//   TB == 1 : B is (N x K) row-major (i.e. compute A @ B^T)
// BM=BN=64, BK=16, 256 threads, 4x4 per thread. M,N % 64 == 0, K % 16 == 0.
// ---------------------------------------------------------------------------
template <int TB>
__global__ __launch_bounds__(256) void gemm64(const float* __restrict__ A,
                                              const float* __restrict__ B,
                                              float* __restrict__ C,
                                              const float* __restrict__ addend,
                                              int M, int N, int K) {
    const int bn = blockIdx.x, bm = blockIdx.y;
    const int tid = threadIdx.x;
    const int tx = tid & 15, ty = tid >> 4;
    const int m0 = bm * 64, n0 = bn * 64;

    __shared__ float As[16][68];   // [kk][m]
    __shared__ float Bs[16][68];   // [kk][n]

    float acc[4][4] = {};

    for (int k0 = 0; k0 < K; k0 += 16) {
        {   // A tile 64x16 -> As[kk][m]
            int kk = tid & 15, m = tid >> 4;
            #pragma unroll
            for (int i = 0; i < 4; ++i)
                As[kk][m + 16 * i] = A[(size_t)(m0 + m + 16 * i) * K + k0 + kk];
        }
        if (TB == 0) {
            int n = tid & 63, kk = tid >> 6;
            #pragma unroll
            for (int i = 0; i < 4; ++i)
                Bs[kk + 4 * i][n] = B[(size_t)(k0 + kk + 4 * i) * N + n0 + n];
        } else {
            int kk = tid & 15, n = tid >> 4;
            #pragma unroll
            for (int i = 0; i < 4; ++i)
                Bs[kk][n + 16 * i] = B[(size_t)(n0 + n + 16 * i) * K + k0 + kk];
        }
        __syncthreads();
        #pragma unroll
        for (int kk = 0; kk < 16; ++kk) {
            float4 a4 = *reinterpret_cast<const float4*>(&As[kk][ty * 4]);
            float4 b4 = *reinterpret_cast<const float4*>(&Bs[kk][tx * 4]);
            float av[4] = {a4.x, a4.y, a4.z, a4.w};
            float bv[4] = {b4.x, b4.y, b4.z, b4.w};
            #pragma unroll
            for (int i = 0; i < 4; ++i)
                #pragma unroll
                for (int j = 0; j < 4; ++j)
                    acc[i][j] += av[i] * bv[j];
        }
        __syncthreads();
    }
    #pragma unroll
    for (int i = 0; i < 4; ++i) {
        int m = m0 + ty * 4 + i;
        #pragma unroll
        for (int j = 0; j < 4; ++j) {
            int n = n0 + tx * 4 + j;
            float v = acc[i][j];
            if (addend) v += addend[(size_t)m * N + n];
            C[(size_t)m * N + n] = v;
        }
    }
}

// ---------------------------------------------------------------------------
// Recurrent scan. Grid (8 slices, 32 batch). 512 threads (8 waves).
// Thread (rloc, kq): row r = slice*64+rloc, cols [kq*64, kq*64+64).
// Weight slice: 16 float4 per thread, STATICALLY indexed -> stays in VGPRs.
// LDS reads XOR-staggered (j = k ^ 2*kq) to break the 8-way bank conflict;
// the register array is filled in the same permuted order so its indexing
// stays compile-time-constant (rule: runtime-indexed arrays go to scratch).
// Spin uses RELAXED polls + one acquire fence (no per-poll buffer_inv).
// ---------------------------------------------------------------------------
__launch_bounds__(512, 2)
__global__ void scan_kernel(const float* __restrict__ Weff,
                            const float* __restrict__ beff,
                            float* __restrict__ u_ys,        // (B,S,H) in/out
                            float* __restrict__ hbufs,       // 2*B*H
                            unsigned int* __restrict__ cnt,  // B counters
                            float leak) {
    const int slice = blockIdx.x;   // 0..7
    const int b = blockIdx.y;       // 0..31
    const int tid = threadIdx.x;    // 0..511
    const int kq = tid & 7;         // col-eighth (64 cols each)
    const int rloc = tid >> 3;      // 0..63
    const int r = slice * 64 + rloc;
    const int sx = kq * 2;          // XOR stagger for bank spread

    __shared__ float hs[HDIM];

    // weight slice -> 16 float4 registers, filled in staggered order so the
    // compute loop pairs w[k] with LDS address (k ^ sx) using static w index.
    float4 w[16];
    {
        const float4* wrow =
            reinterpret_cast<const float4*>(Weff + (size_t)r * HDIM + kq * 64);
        #pragma unroll
        for (int k = 0; k < 16; ++k) w[k] = wrow[k ^ sx];
    }
    const float be = beff[r];
    const float lk = leak, olk = 1.0f - leak;
    float* ub = u_ys + (size_t)b * SEQ * HDIM;
    unsigned int* cb = cnt + b;

    float u_cur = ub[r];   // u for t=0

    for (int t = 0; t < SEQ; ++t) {
        const float* hr = hbufs + (size_t)(t & 1) * BATCH * HDIM + (size_t)b * HDIM;
        float* hw = hbufs + (size_t)((t + 1) & 1) * BATCH * HDIM + (size_t)b * HDIM;

        // previous h -> LDS (cache-bypassing agent-scope load, 1 float/thread)
        hs[tid] = __hip_atomic_load(hr + tid, __ATOMIC_RELAXED, __HIP_MEMORY_SCOPE_AGENT);
        // prefetch u for next step (independent of recurrence)
        float u_next = 0.f;
        if (t + 1 < SEQ) u_next = ub[(size_t)(t + 1) * HDIM + r];
        __syncthreads();

        // matvec: row r, cols [kq*64, kq*64+64), XOR-staggered LDS order
        float acc = 0.f;
        const float* hq = hs + kq * 64;
        #pragma unroll
        for (int k = 0; k < 16; ++k) {
            float4 h4 = *reinterpret_cast<const float4*>(hq + 4 * (k ^ sx));
            acc += w[k].x * h4.x + w[k].y * h4.y + w[k].z * h4.z + w[k].w * h4.w;
        }
        acc += __shfl_xor(acc, 1);
        acc += __shfl_xor(acc, 2);
        acc += __shfl_xor(acc, 4);

        if (kq == 0) {
            float pre = acc + u_cur + be;
            float hn = tanhf(pre);
            float hnew = olk * hs[r] + lk * hn;
            __hip_atomic_store(hw + r, hnew, __ATOMIC_RELAXED, __HIP_MEMORY_SCOPE_AGENT);
            ub[(size_t)t * HDIM + r] = hnew;   // ys output, in place over u
        }
        u_cur = u_next;
        __syncthreads();   // all stores drained (vmcnt 0) before counter bump

        // inter-WG barrier for this batch element (monotonic counter)
        if (tid == 0) {
            __hip_atomic_fetch_add(cb, 1u, __ATOMIC_RELEASE, __HIP_MEMORY_SCOPE_AGENT);
            const unsigned int target = 8u * (unsigned)(t + 1);
            while (__hip_atomic_load(cb, __ATOMIC_RELAXED, __HIP_MEMORY_SCOPE_AGENT) < target) {
            }
            __builtin_amdgcn_fence(__ATOMIC_ACQUIRE, "agent");
        }
        __syncthreads();
    }
}

// ---------------------------------------------------------------------------
extern "C" void kernel_launch(void* const* d_in, const int* in_sizes, int n_in,
                              void* d_out, int out_size, void* d_ws, size_t ws_size,
                              hipStream_t stream) {
    const float* x      = (const float*)d_in[0];
    const int*   edges  = (const int*)d_in[1];
    const float* W_in0  = (const float*)d_in[2];
    const float* W_res0 = (const float*)d_in[3];
    const float* bias0  = (const float*)d_in[4];
    const float* Wp0    = (const float*)d_in[5];
    const float* bp0    = (const float*)d_in[6];
    const float* Wu0    = (const float*)d_in[7];
    const float* bu0    = (const float*)d_in[8];
    const float* W_in1  = (const float*)d_in[9];
    const float* W_res1 = (const float*)d_in[10];
    const float* bias1  = (const float*)d_in[11];
    const float* Wp1    = (const float*)d_in[12];
    const float* bp1    = (const float*)d_in[13];
    const float* Wu1    = (const float*)d_in[14];
    const float* bu1    = (const float*)d_in[15];

    const int* src = edges;
    const int* dst = edges + NEDGES;
    float* out = (float*)d_out;

    // workspace layout
    char* base = (char*)d_ws;
    float* ws_u  = (float*)base;                 // 32*1024*512*4 = 67,108,864
    char* p = base + (size_t)67108864;
    float* AWp   = (float*)p;  p += 2097152;     // 1024*512*4
    float* Abp   = (float*)p;  p += 4096;        // 1024*4
    float* Weff0 = (float*)p;  p += 1048576;     // 512*512*4
    float* Weff1 = (float*)p;  p += 1048576;
    float* beff0 = (float*)p;  p += 2048;
    float* beff1 = (float*)p;  p += 2048;
    float* hbufs = (float*)p;  p += 131072;      // 2*32*512*4
    unsigned int* cnt = (unsigned int*)p;        // 64 uints (2 scans x 32)

    // ---- layer 0 effective weights ----
    hipMemsetAsync(AWp, 0, 2097152 + 4096, stream);
    scatter_awp_kernel<<<NEDGES, 256, 0, stream>>>(Wp0, src, dst, AWp);
    scatter_abp_kernel<<<NEDGES / 256, 256, 0, stream>>>(bp0, src, dst, Abp);
    gemm64<0><<<dim3(8, 8), 256, 0, stream>>>(Wu0, AWp, Weff0, W_res0, 512, 512, 1024);
    beff_kernel<<<1, 512, 0, stream>>>(Wu0, Abp, bias0, bu0, beff0);

    // ---- layer 1 effective weights ----
    hipMemsetAsync(AWp, 0, 2097152 + 4096, stream);
    scatter_awp_kernel<<<NEDGES, 256, 0, stream>>>(Wp1, src, dst, AWp);
    scatter_abp_kernel<<<NEDGES / 256, 256, 0, stream>>>(bp1, src, dst, Abp);
    gemm64<0><<<dim3(8, 8), 256, 0, stream>>>(Wu1, AWp, Weff1, W_res1, 512, 512, 1024);
    beff_kernel<<<1, 512, 0, stream>>>(Wu1, Abp, bias1, bu1, beff1);

    // ---- u0 = x @ W_in0^T : (32768 x 128) @ (512 x 128)^T ----
    gemm64<1><<<dim3(512 / 64, 32768 / 64), 256, 0, stream>>>(
        x, W_in0, ws_u, nullptr, BATCH * SEQ, HDIM, DIN);

    // ---- layer 0 scan (in place over ws_u) ----
    hipMemsetAsync(hbufs, 0, 131072 + 256, stream);
    scan_kernel<<<dim3(8, BATCH), 512, 0, stream>>>(Weff0, beff0, ws_u, hbufs, cnt, 0.1f);

    // ---- u1 = ys0 @ W_in1^T : (32768 x 512) @ (512 x 512)^T -> d_out ----
    gemm64<1><<<dim3(512 / 64, 32768 / 64), 256, 0, stream>>>(
        ws_u, W_in1, out, nullptr, BATCH * SEQ, HDIM, HDIM);

    // ---- layer 1 scan (in place over d_out) ----
    hipMemsetAsync(hbufs, 0, 131072, stream);
    scan_kernel<<<dim3(8, BATCH), 512, 0, stream>>>(Weff1, beff1, out, hbufs, cnt + BATCH, 0.15f);
}

// Round 3
// 4398.312 us; speedup vs baseline: 8.4317x; 7.0020x over previous
//
#include <hip/hip_runtime.h>
#include <hip/hip_bf16.h>
#include <cstddef>
#include <cstdint>

#define HDIM 512
#define NNODES 1024
#define NEDGES 16384
#define BATCH 32
#define SEQ 1024
#define DIN 128

// ---------------------------------------------------------------------------
// Precompute: AWp[d][j] = sum_{e: dst_e=d} Wp[src_e][j]
// ---------------------------------------------------------------------------
__global__ void scatter_awp_kernel(const float* __restrict__ Wp,
                                   const int* __restrict__ src,
                                   const int* __restrict__ dst,
                                   float* __restrict__ AWp) {
    int e = blockIdx.x;        // 16384 blocks
    int c = threadIdx.x;       // 256 threads, 2 cols each
    int s = src[e], d = dst[e];
    atomicAdd(&AWp[d * HDIM + c],        Wp[s * HDIM + c]);
    atomicAdd(&AWp[d * HDIM + 256 + c],  Wp[s * HDIM + 256 + c]);
}

__global__ void scatter_abp_kernel(const float* __restrict__ bp,
                                   const int* __restrict__ src,
                                   const int* __restrict__ dst,
                                   float* __restrict__ Abp) {
    int e = blockIdx.x * blockDim.x + threadIdx.x;
    if (e < NEDGES) atomicAdd(&Abp[dst[e]], bp[src[e]]);
}

// b_eff[i] = bias[i] + bu[i] + sum_d Wu[i][d] * Abp[d]
__global__ void beff_kernel(const float* __restrict__ Wu,
                            const float* __restrict__ Abp,
                            const float* __restrict__ bias,
                            const float* __restrict__ bu,
                            float* __restrict__ beff) {
    int i = threadIdx.x;       // 512 threads, 1 block
    float s = 0.f;
    for (int d = 0; d < NNODES; ++d) s += Wu[i * NNODES + d] * Abp[d];
    beff[i] = bias[i] + bu[i] + s;
}

// ---------------------------------------------------------------------------
// fp32 tiled GEMM: C[m][n] = sum_k A[m][k] * B_(k,n)  (+ optional addend)
//   TB == 0 : B is (K x N) row-major
//   TB == 1 : B is (N x K) row-major (i.e. compute A @ B^T)
// BM=BN=64, BK=16, 256 threads, 4x4 per thread. M,N % 64 == 0, K % 16 == 0.
// ---------------------------------------------------------------------------
template <int TB>
__global__ __launch_bounds__(256) void gemm64(const float* __restrict__ A,
                                              const float* __restrict__ B,
                                              float* __restrict__ C,
                                              const float* __restrict__ addend,
                                              int M, int N, int K) {
    const int bn = blockIdx.x, bm = blockIdx.y;
    const int tid = threadIdx.x;
    const int tx = tid & 15, ty = tid >> 4;
    const int m0 = bm * 64, n0 = bn * 64;

    __shared__ float As[16][68];   // [kk][m]
    __shared__ float Bs[16][68];   // [kk][n]

    float acc[4][4] = {};

    for (int k0 = 0; k0 < K; k0 += 16) {
        {   // A tile 64x16 -> As[kk][m]
            int kk = tid & 15, m = tid >> 4;
            #pragma unroll
            for (int i = 0; i < 4; ++i)
                As[kk][m + 16 * i] = A[(size_t)(m0 + m + 16 * i) * K + k0 + kk];
        }
        if (TB == 0) {
            int n = tid & 63, kk = tid >> 6;
            #pragma unroll
            for (int i = 0; i < 4; ++i)
                Bs[kk + 4 * i][n] = B[(size_t)(k0 + kk + 4 * i) * N + n0 + n];
        } else {
            int kk = tid & 15, n = tid >> 4;
            #pragma unroll
            for (int i = 0; i < 4; ++i)
                Bs[kk][n + 16 * i] = B[(size_t)(n0 + n + 16 * i) * K + k0 + kk];
        }
        __syncthreads();
        #pragma unroll
        for (int kk = 0; kk < 16; ++kk) {
            float4 a4 = *reinterpret_cast<const float4*>(&As[kk][ty * 4]);
            float4 b4 = *reinterpret_cast<const float4*>(&Bs[kk][tx * 4]);
            float av[4] = {a4.x, a4.y, a4.z, a4.w};
            float bv[4] = {b4.x, b4.y, b4.z, b4.w};
            #pragma unroll
            for (int i = 0; i < 4; ++i)
                #pragma unroll
                for (int j = 0; j < 4; ++j)
                    acc[i][j] += av[i] * bv[j];
        }
        __syncthreads();
    }
    #pragma unroll
    for (int i = 0; i < 4; ++i) {
        int m = m0 + ty * 4 + i;
        #pragma unroll
        for (int j = 0; j < 4; ++j) {
            int n = n0 + tx * 4 + j;
            float v = acc[i][j];
            if (addend) v += addend[(size_t)m * N + n];
            C[(size_t)m * N + n] = v;
        }
    }
}

// ---------------------------------------------------------------------------
// Recurrent scan. Grid (8 slices, 32 batch). 512 threads (8 waves).
// Thread (rloc, kq): row r = slice*64+rloc, cols [kq*64, kq*64+64).
//
// Sync: NO counters, NO fences. h is exchanged as (value, step-tag) packed
// into one 8-byte relaxed agent-scope atomic store; each thread polls its
// own 8B pair until the tag matches the step. Double-buffered slots (t&1);
// single __syncthreads per step with double-buffered LDS (max wave skew is
// one step, so buffer parity protects both LDS and the global slots).
// Weights pinned in VGPRs via opaque asm identity (blocks rematerialization
// that R2's VGPR_Count=56 exposed). No release/acquire anywhere -> no
// buffer_wbl2 / buffer_inv L2 carnage; all shared data moves through
// cache-bypassing relaxed agent atomics.
// ---------------------------------------------------------------------------
__launch_bounds__(512, 1)
__global__ void scan_kernel(const float* __restrict__ Weff,
                            const float* __restrict__ beff,
                            float* __restrict__ u_ys,              // (B,S,H) in/out
                            unsigned long long* __restrict__ hpair, // [2][B][H]
                            float leak) {
    const int slice = blockIdx.x;   // 0..7
    const int b = blockIdx.y;       // 0..31
    const int tid = threadIdx.x;    // 0..511
    const int kq = tid & 7;         // col-eighth (64 cols each)
    const int rloc = tid >> 3;      // 0..63
    const int r = slice * 64 + rloc;
    const int sx = kq * 2;          // XOR stagger (R2: conflicts -> 0)

    __shared__ float hs[2][HDIM];

    // weight slice -> 16 float4 registers, staggered order (static indexing)
    float4 w[16];
    {
        const float4* wrow =
            reinterpret_cast<const float4*>(Weff + (size_t)r * HDIM + kq * 64);
        #pragma unroll
        for (int k = 0; k < 16; ++k) w[k] = wrow[k ^ sx];
    }
    // pin in VGPRs: opaque identity, cannot be rematerialized or sunk
    #pragma unroll
    for (int k = 0; k < 16; ++k)
        asm volatile("" : "+v"(w[k].x), "+v"(w[k].y), "+v"(w[k].z), "+v"(w[k].w));

    const float be = beff[r];
    const float lk = leak, olk = 1.0f - leak;
    float* ub = u_ys + (size_t)b * SEQ * HDIM;
    unsigned long long* hb = hpair + (size_t)b * HDIM;
    const size_t slotstride = (size_t)BATCH * HDIM;

    for (int t = 0; t < SEQ; ++t) {
        // u for this step (only kq==0 consumes); issue before the poll so the
        // HBM/L2 latency hides under the spin.
        float u_t = 0.f;
        if (kq == 0) u_t = ub[(size_t)t * HDIM + r];

        // poll own row's (h, tag) pair for tag == t
        const unsigned long long* slotp = hb + (size_t)(t & 1) * slotstride + tid;
        unsigned long long v;
        do {
            v = __hip_atomic_load(slotp, __ATOMIC_RELAXED, __HIP_MEMORY_SCOPE_AGENT);
        } while ((unsigned)(v >> 32) != (unsigned)t);
        hs[t & 1][tid] = __uint_as_float((unsigned)v);
        __syncthreads();

        // matvec: row r, cols [kq*64, kq*64+64), XOR-staggered LDS order
        float acc = 0.f;
        const float* hq = &hs[t & 1][kq * 64];
        #pragma unroll
        for (int k = 0; k < 16; ++k) {
            float4 h4 = *reinterpret_cast<const float4*>(hq + 4 * (k ^ sx));
            acc += w[k].x * h4.x + w[k].y * h4.y + w[k].z * h4.z + w[k].w * h4.w;
        }
        acc += __shfl_xor(acc, 1);
        acc += __shfl_xor(acc, 2);
        acc += __shfl_xor(acc, 4);

        if (kq == 0) {
            float pre = acc + u_t + be;
            float hn = tanhf(pre);
            float hnew = olk * hs[t & 1][r] + lk * hn;
            unsigned long long pv =
                ((unsigned long long)(unsigned)(t + 1) << 32) | __float_as_uint(hnew);
            __hip_atomic_store(hb + (size_t)((t + 1) & 1) * slotstride + r, pv,
                               __ATOMIC_RELAXED, __HIP_MEMORY_SCOPE_AGENT);
            ub[(size_t)t * HDIM + r] = hnew;   // ys output, in place over u
        }
        // no end-of-step barrier needed: LDS + slot double-buffering covers
        // the max one-step wave skew (a wave can't pass step t+1's
        // __syncthreads until every peer stored tag t+1).
    }
}

// ---------------------------------------------------------------------------
extern "C" void kernel_launch(void* const* d_in, const int* in_sizes, int n_in,
                              void* d_out, int out_size, void* d_ws, size_t ws_size,
                              hipStream_t stream) {
    const float* x      = (const float*)d_in[0];
    const int*   edges  = (const int*)d_in[1];
    const float* W_in0  = (const float*)d_in[2];
    const float* W_res0 = (const float*)d_in[3];
    const float* bias0  = (const float*)d_in[4];
    const float* Wp0    = (const float*)d_in[5];
    const float* bp0    = (const float*)d_in[6];
    const float* Wu0    = (const float*)d_in[7];
    const float* bu0    = (const float*)d_in[8];
    const float* W_in1  = (const float*)d_in[9];
    const float* W_res1 = (const float*)d_in[10];
    const float* bias1  = (const float*)d_in[11];
    const float* Wp1    = (const float*)d_in[12];
    const float* bp1    = (const float*)d_in[13];
    const float* Wu1    = (const float*)d_in[14];
    const float* bu1    = (const float*)d_in[15];

    const int* src = edges;
    const int* dst = edges + NEDGES;
    float* out = (float*)d_out;

    // workspace layout
    char* base = (char*)d_ws;
    float* ws_u  = (float*)base;                 // 32*1024*512*4 = 67,108,864
    char* p = base + (size_t)67108864;
    float* AWp   = (float*)p;  p += 2097152;     // 1024*512*4
    float* Abp   = (float*)p;  p += 4096;        // 1024*4
    float* Weff0 = (float*)p;  p += 1048576;     // 512*512*4
    float* Weff1 = (float*)p;  p += 1048576;
    float* beff0 = (float*)p;  p += 2048;
    float* beff1 = (float*)p;  p += 2048;
    unsigned long long* hpair = (unsigned long long*)p;  // 2*32*512*8 = 262144
    p += 262144;

    // ---- layer 0 effective weights ----
    hipMemsetAsync(AWp, 0, 2097152 + 4096, stream);
    scatter_awp_kernel<<<NEDGES, 256, 0, stream>>>(Wp0, src, dst, AWp);
    scatter_abp_kernel<<<NEDGES / 256, 256, 0, stream>>>(bp0, src, dst, Abp);
    gemm64<0><<<dim3(8, 8), 256, 0, stream>>>(Wu0, AWp, Weff0, W_res0, 512, 512, 1024);
    beff_kernel<<<1, 512, 0, stream>>>(Wu0, Abp, bias0, bu0, beff0);

    // ---- layer 1 effective weights ----
    hipMemsetAsync(AWp, 0, 2097152 + 4096, stream);
    scatter_awp_kernel<<<NEDGES, 256, 0, stream>>>(Wp1, src, dst, AWp);
    scatter_abp_kernel<<<NEDGES / 256, 256, 0, stream>>>(bp1, src, dst, Abp);
    gemm64<0><<<dim3(8, 8), 256, 0, stream>>>(Wu1, AWp, Weff1, W_res1, 512, 512, 1024);
    beff_kernel<<<1, 512, 0, stream>>>(Wu1, Abp, bias1, bu1, beff1);

    // ---- u0 = x @ W_in0^T : (32768 x 128) @ (512 x 128)^T ----
    gemm64<1><<<dim3(512 / 64, 32768 / 64), 256, 0, stream>>>(
        x, W_in0, ws_u, nullptr, BATCH * SEQ, HDIM, DIN);

    // ---- layer 0 scan (in place over ws_u) ----
    hipMemsetAsync(hpair, 0, 262144, stream);   // tags start at 0, h0 = 0
    scan_kernel<<<dim3(8, BATCH), 512, 0, stream>>>(Weff0, beff0, ws_u, hpair, 0.1f);

    // ---- u1 = ys0 @ W_in1^T : (32768 x 512) @ (512 x 512)^T -> d_out ----
    gemm64<1><<<dim3(512 / 64, 32768 / 64), 256, 0, stream>>>(
        ws_u, W_in1, out, nullptr, BATCH * SEQ, HDIM, HDIM);

    // ---- layer 1 scan (in place over d_out) ----
    hipMemsetAsync(hpair, 0, 262144, stream);
    scan_kernel<<<dim3(8, BATCH), 512, 0, stream>>>(Weff1, beff1, out, hpair, 0.15f);
}